// Round 1
// 296.455 us; speedup vs baseline: 1.0494x; 1.0494x over previous
//
#include <hip/hip_runtime.h>
#include <hip/hip_bf16.h>

// B=64, L=512, H2=1536, T=64. logits = x@W + b -> softmax -> loss/acc.
// R5: 4-wave blocks with LDS-shared B fragments.
//   - R4 re-read the full 384KB B-fragment array from L2 per wave:
//     2048 waves x 384KB = 786 MB L2 traffic (~22 TB/s demand at a ~35us
//     main), 16 of 20 vmem issues/lane/iter. R5 stages each 16KB B chunk
//     in LDS once per 4-wave block: 196 MB L2 traffic, 8 issues/lane/iter.
//   - All global->LDS movement is global_load_lds DMA (un-sinkable by the
//     compiler; the R2/R3 register-prefetch designs were legally defeated).
//   - 512 blocks x 256 thr, 64 KB LDS -> 2 blocks/CU x 4 waves = 8 waves/CU
//     (same occupancy as R4), grid exactly 2/CU, no tail.
//   - Per-wave x swizzle, MFMA math, epilogue identical to R4 (verified,
//     absmax 0.0); only the row base and the B path changed.

#define H2 1536
#define NT 64
#define ROWS (64 * 512)
#define KC 64                 // k per LDS buffer
#define NITER (H2 / KC)       // 24
#define KS2 (H2 / 32)         // 48 MFMA k-steps (B-fragment granularity)
#define NBLK (ROWS / 64)      // 512 blocks, 4 waves each

typedef __attribute__((ext_vector_type(8))) short short8;
typedef __attribute__((ext_vector_type(4))) float f32x4;

#define B_FRAGS (KS2 * 4 * 64)   // 12288 fragments x 16B (hi), same (lo)

__device__ __forceinline__ short bf_hi(float f) {
    __hip_bfloat16 h = __float2bfloat16(f);          // RNE
    return __builtin_bit_cast(short, h);
}
__device__ __forceinline__ float bf_f(short s) {
    __hip_bfloat16 h = __builtin_bit_cast(__hip_bfloat16, s);
    return __bfloat162float(h);
}

// Pack W[k][n] ([1536][64] k-major) into MFMA B-fragment order.
// Fragment (s2, c, lane): k = s2*32 + (lane>>4)*8 + j, n = c*16 + (lane&15).
__global__ void mlaner_prepw(const float* __restrict__ W,
                             short8* __restrict__ bhi, short8* __restrict__ blo)
{
    const int tid = blockIdx.x * 256 + threadIdx.x;   // 0..12287
    const int L = tid & 63, c = (tid >> 6) & 3, s2 = tid >> 8;
    const int kbase = s2 * 32 + (L >> 4) * 8;
    const int n = c * 16 + (L & 15);
    short8 hi, lo;
#pragma unroll
    for (int j = 0; j < 8; ++j) {
        float w = W[(size_t)(kbase + j) * NT + n];
        short h = bf_hi(w);
        hi[j] = h;
        lo[j] = bf_hi(w - bf_f(h));
    }
    const int idx = (s2 * 4 + c) * 64 + L;
    bhi[idx] = hi;
    blo[idx] = lo;
}

__device__ __forceinline__ void cvt_split(float4 a0, float4 a1,
                                          short8& hi, short8& lo)
{
    float v[8] = {a0.x, a0.y, a0.z, a0.w, a1.x, a1.y, a1.z, a1.w};
#pragma unroll
    for (int j = 0; j < 8; ++j) {
        short h = bf_hi(v[j]);
        hi[j] = h;
        lo[j] = bf_hi(v[j] - bf_f(h));
    }
}

__global__ __launch_bounds__(256, 2) void mlaner_main(
    const float* __restrict__ x,
    const short8* __restrict__ Bhi, const short8* __restrict__ Blo,
    const float* __restrict__ bias, const int* __restrict__ tags,
    const float* __restrict__ tag_to_score, const int* __restrict__ tptr,
    float* __restrict__ ploss, unsigned* __restrict__ pright,
    unsigned* __restrict__ pvalid)
{
    __shared__ __align__(16) float xbuf[2][4][KC * 16];   // 2 x 4 waves x 4KB
    __shared__ short8 bbuf[2][2][512];                    // 2 x {hi,lo} x 8KB

    const int tid = threadIdx.x;
    const int lane = tid & 63;
    const int wave = tid >> 6;
    const int blk = blockIdx.x;
    const int row0 = blk * 64 + wave * 16;    // this wave's 16 rows
    const int q = lane >> 4, n16 = lane & 15;

    // Stage chunk s into buffer b:
    //  x: each wave DMAs its own 16 rows x 64 k (4KB, 4 x 1KB issues).
    //     LDS dest is wave-uniform base + lane*16 (HW rule). Global side
    //     applies the bank swizzle: slot j of row r holds global k-slot
    //     j^(r&7).
    //  B: the 16KB fragment chunk (8KB hi + 8KB lo) is DMA'd once per
    //     block, wave w covering KBs {2w,2w+1}. Linear both sides --
    //     fragments are consumed lane-contiguously, no swizzle needed.
    auto stage = [&](int b, int s) {
#pragma unroll
        for (int i = 0; i < 4; ++i) {
            const int idx = i * 64 + lane;          // 0..255 slot index
            const int r = idx >> 4, j = idx & 15;
            const int jg = j ^ (r & 7);
            const float* gp = x + (size_t)(row0 + r) * H2 + s * KC + jg * 4;
            __builtin_amdgcn_global_load_lds(
                (const __attribute__((address_space(1))) void*)gp,
                (__attribute__((address_space(3))) void*)&xbuf[b][wave][i * 256],
                16, 0, 0);
        }
#pragma unroll
        for (int i = 0; i < 2; ++i) {
            const int kb = wave * 2 + i;            // 0..7: KB within chunk
            const short8* gh = Bhi + (size_t)s * 512 + kb * 64 + lane;
            __builtin_amdgcn_global_load_lds(
                (const __attribute__((address_space(1))) void*)gh,
                (__attribute__((address_space(3))) void*)&bbuf[b][0][kb * 64],
                16, 0, 0);
            const short8* gl = Blo + (size_t)s * 512 + kb * 64 + lane;
            __builtin_amdgcn_global_load_lds(
                (const __attribute__((address_space(1))) void*)gl,
                (__attribute__((address_space(3))) void*)&bbuf[b][1][kb * 64],
                16, 0, 0);
        }
    };

    f32x4 acc[4];
#pragma unroll
    for (int c = 0; c < 4; ++c) acc[c] = (f32x4){0.f, 0.f, 0.f, 0.f};

    stage(0, 0);
    __syncthreads();                       // drain stage(0)

#pragma unroll 1
    for (int s = 0; s < NITER; ++s) {
        if (s + 1 < NITER) stage((s + 1) & 1, s + 1);   // prefetch DMA

        const int cur = s & 1;
        const float* bufp = &xbuf[cur][wave][0];
#pragma unroll
        for (int h = 0; h < 2; ++h) {
            // B fragments from LDS: lane-contiguous ds_read_b128, no
            // conflicts (lane l reads bytes [l*16, l*16+16)).
            short8 bh[4], bl[4];
#pragma unroll
            for (int c = 0; c < 4; ++c) {
                bh[c] = bbuf[cur][0][(h * 4 + c) * 64 + lane];
                bl[c] = bbuf[cur][1][(h * 4 + c) * 64 + lane];
            }
            // A-fragment: lane(q,n16) = row n16, k = h*32 + q*8 + [0..8)
            const int sg0 = (h * 8 + 2 * q)     ^ (n16 & 7);
            const int sg1 = (h * 8 + 2 * q + 1) ^ (n16 & 7);
            float4 a0 = *(const float4*)&bufp[n16 * 64 + sg0 * 4];
            float4 a1 = *(const float4*)&bufp[n16 * 64 + sg1 * 4];
            short8 ah, al;
            cvt_split(a0, a1, ah, al);
#pragma unroll
            for (int c = 0; c < 4; ++c) {
                acc[c] = __builtin_amdgcn_mfma_f32_16x16x32_bf16(ah, bh[c], acc[c], 0, 0, 0);
                acc[c] = __builtin_amdgcn_mfma_f32_16x16x32_bf16(ah, bl[c], acc[c], 0, 0, 0);
                acc[c] = __builtin_amdgcn_mfma_f32_16x16x32_bf16(al, bh[c], acc[c], 0, 0, 0);
            }
        }
        __syncthreads();   // drain prefetch DMA; protect buffer reuse
    }

    // ---- epilogue (per wave, identical to R4) ----
    // C/D layout: col = c*16 + n16, row(local) = q*4 + i  [m89-verified]
    // attention_mask adds a row constant -> softmax/argmax invariant; skipped.
    const float bv0 = bias[n16], bv1 = bias[16 + n16];
    const float bv2 = bias[32 + n16], bv3 = bias[48 + n16];
    int tg[4];
#pragma unroll
    for (int i = 0; i < 4; ++i) tg[i] = tags[row0 + q * 4 + i];
    const int tt = tptr[0];
    const float e1c = expf(1.0f);
    float loss_acc = 0.0f;
    unsigned right_acc = 0, valid_acc = 0;

#pragma unroll 1
    for (int i = 0; i < 4; ++i) {
        float l0 = acc[0][i] + bv0, l1 = acc[1][i] + bv1;
        float l2 = acc[2][i] + bv2, l3 = acc[3][i] + bv3;

        float m = fmaxf(fmaxf(l0, l1), fmaxf(l2, l3));
#pragma unroll
        for (int off = 8; off >= 1; off >>= 1)
            m = fmaxf(m, __shfl_xor(m, off, 64));

        float e0 = expf(l0 - m), e1 = expf(l1 - m);
        float e2 = expf(l2 - m), e3 = expf(l3 - m);
        float Z = e0 + e1 + e2 + e3;
#pragma unroll
        for (int off = 8; off >= 1; off >>= 1)
            Z += __shfl_xor(Z, off, 64);

        float lp0 = logf(e0 / Z + 1e-10f), lp1 = logf(e1 / Z + 1e-10f);
        float lp2 = logf(e2 / Z + 1e-10f), lp3 = logf(e3 / Z + 1e-10f);
        float slp = lp0 + lp1 + lp2 + lp3;
#pragma unroll
        for (int off = 8; off >= 1; off >>= 1)
            slp += __shfl_xor(slp, off, 64);

        // argmax, numpy first-index tie semantics
        float bval = l0; int bcol = n16;
        if (l1 > bval) { bval = l1; bcol = 16 + n16; }
        if (l2 > bval) { bval = l2; bcol = 32 + n16; }
        if (l3 > bval) { bval = l3; bcol = 48 + n16; }
#pragma unroll
        for (int off = 8; off >= 1; off >>= 1) {
            float ov = __shfl_xor(bval, off, 64);
            int   oc = __shfl_xor(bcol, off, 64);
            if (ov > bval || (ov == bval && oc < bcol)) { bval = ov; bcol = oc; }
        }

        const int tag = tg[i];                 // uniform within 16-lane group
        const int csel = tag >> 4;
        float cand = (csel == 0) ? lp0 : (csel == 1) ? lp1 : (csel == 2) ? lp2 : lp3;
        float lptag = __shfl(cand, (lane & 48) | (tag & 15), 64);

        float sc = tag_to_score[tag];
        float sp = (tt == 2) ? sc * sc : powf(sc, (float)tt);
        float es = expf(sp);
        float denom = 63.0f * e1c + es;
        float rowloss = -((e1c / denom) * (slp - lptag) + (es / denom) * lptag);

        if (n16 == 0) {
            loss_acc += rowloss;
            unsigned valid = (tag < NT - 3) ? 1u : 0u;
            valid_acc += valid;
            right_acc += (valid && bcol == tag) ? 1u : 0u;
        }
    }

#pragma unroll
    for (int off = 32; off >= 1; off >>= 1) {
        loss_acc += __shfl_xor(loss_acc, off, 64);
        right_acc += __shfl_xor((int)right_acc, off, 64);
        valid_acc += __shfl_xor((int)valid_acc, off, 64);
    }

    // cross-wave combine via xbuf reuse (safe: last K-iter barrier passed,
    // no further xbuf reads/DMA writes).
    float* redf = &xbuf[0][0][0];
    unsigned* redu = (unsigned*)&xbuf[0][1][0];
    unsigned* redv = (unsigned*)&xbuf[0][2][0];
    if (lane == 0) { redf[wave] = loss_acc; redu[wave] = right_acc; redv[wave] = valid_acc; }
    __syncthreads();
    if (tid == 0) {
        ploss[blk] = redf[0] + redf[1] + redf[2] + redf[3];
        pright[blk] = redu[0] + redu[1] + redu[2] + redu[3];
        pvalid[blk] = redv[0] + redv[1] + redv[2] + redv[3];
    }
}

__global__ void mlaner_final(const float* __restrict__ pl,
                             const unsigned* __restrict__ pr,
                             const unsigned* __restrict__ pv,
                             float* __restrict__ out)
{
    __shared__ float sl[4];
    __shared__ unsigned sr[4], sv[4];
    const int tid = threadIdx.x, lane = tid & 63, wv = tid >> 6;
    float l = 0.0f; unsigned r = 0, v = 0;
    for (int i = tid; i < NBLK; i += 256) { l += pl[i]; r += pr[i]; v += pv[i]; }
#pragma unroll
    for (int off = 32; off >= 1; off >>= 1) {
        l += __shfl_xor(l, off, 64);
        r += __shfl_xor((int)r, off, 64);
        v += __shfl_xor((int)v, off, 64);
    }
    if (lane == 0) { sl[wv] = l; sr[wv] = r; sv[wv] = v; }
    __syncthreads();
    if (tid == 0) {
        float L = sl[0] + sl[1] + sl[2] + sl[3];
        unsigned R = sr[0] + sr[1] + sr[2] + sr[3];
        unsigned V = sv[0] + sv[1] + sv[2] + sv[3];
        out[0] = L;
        out[1] = (float)R / (float)V;
    }
}

extern "C" void kernel_launch(void* const* d_in, const int* in_sizes, int n_in,
                              void* d_out, int out_size, void* d_ws, size_t ws_size,
                              hipStream_t stream)
{
    const float* x    = (const float*)d_in[0];   // [64,512,1536] fp32
    const float* W    = (const float*)d_in[1];   // [1536,64] fp32
    const float* b    = (const float*)d_in[2];   // [64] fp32
    const int*   tags = (const int*)d_in[3];     // [64,512]
    // d_in[4]: attention_mask — softmax-shift-invariant, unused.
    const float* t2s  = (const float*)d_in[5];   // [64] fp32
    const int*   tptr = (const int*)d_in[6];     // scalar t
    float* out = (float*)d_out;                  // [loss1, acc1]

    // ws layout: Bhi | Blo | ploss[512] | pright[512] | pvalid[512]
    short8* bhi = (short8*)d_ws;
    short8* blo = bhi + B_FRAGS;
    float* ploss = (float*)((char*)d_ws + (size_t)2 * B_FRAGS * 16);
    unsigned* pright = (unsigned*)(ploss + NBLK);
    unsigned* pvalid = pright + NBLK;
    // needs ws_size >= 393216 + 6144 bytes

    mlaner_prepw<<<dim3(B_FRAGS / 256), dim3(256), 0, stream>>>(W, bhi, blo);
    mlaner_main<<<dim3(NBLK), dim3(256), 0, stream>>>(
        x, bhi, blo, b, tags, t2s, tptr, ploss, pright, pvalid);
    mlaner_final<<<dim3(1), dim3(256), 0, stream>>>(ploss, pright, pvalid, out);
}